// Round 5
// baseline (291.645 us; speedup 1.0000x reference)
//
#include <hip/hip_runtime.h>
#include <hip/hip_bf16.h>
#include <math.h>

// ---------------------------------------------------------------------------
// DualHeadGAT R5: chunked in-wave dedup of edge-coefficient computation
// (1 exp per (edge,head) instead of 16x/64x redundant), readlane-scalarized
// gather addressing. bf16 feature gathers, MFMA GEMMs with fused att dots,
// CSR gather aggregation, implicit self-loops, deferred softmax (exact).
// N=50000, IN=128, E=800000. f32 in/out, int32 edges.
// ---------------------------------------------------------------------------

#define LRELU_SLOPE 0.2f

typedef __attribute__((ext_vector_type(8))) short short8;   // 8 bf16 = 4 VGPR
typedef __attribute__((ext_vector_type(4))) float f32x4;

__device__ inline ushort f2bf(float f) {            // RNE f32 -> bf16
    uint u = __float_as_uint(f);
    return (ushort)((u + 0x7FFFu + ((u >> 16) & 1u)) >> 16);
}
__device__ inline float bf2f(ushort u) {
    return __uint_as_float(((uint)u) << 16);
}
__device__ inline float readlane_f(float v, int l) {
    return __uint_as_float(__builtin_amdgcn_readlane(__float_as_uint(v), l));
}

// ---------------- x (f32) -> bf16, 4 elems/thread --------------------------
__global__ __launch_bounds__(256)
void conv_bf16(const float* __restrict__ in, ushort* __restrict__ out, int n)
{
    int i = (blockIdx.x * blockDim.x + threadIdx.x) << 2;
    if (i >= n) return;
    float4 v = *(const float4*)(in + i);
    ushort4 o;
    o.x = f2bf(v.x); o.y = f2bf(v.y); o.z = f2bf(v.z); o.w = f2bf(v.w);
    *(ushort4*)(out + i) = o;
}

// ------- pre-fragment W[K][16J] (f32, row-major) into MFMA B-frag order ----
__global__ __launch_bounds__(256)
void prefrag(const float* __restrict__ W, ushort* __restrict__ out,
             int J, int T, int ldn)
{
    int tid = blockIdx.x * blockDim.x + threadIdx.x;
    if (tid >= J * T * 64) return;
    int l = tid & 63, jt = tid >> 6;
    int t = jt % T, j = jt / T;
    int n = j * 16 + (l & 15);
    int k0 = t * 32 + (l >> 4) * 8;
    ushort o[8];
    #pragma unroll
    for (int b = 0; b < 8; ++b) o[b] = f2bf(W[(size_t)(k0 + b) * ldn + n]);
    *(short8*)(out + (size_t)tid * 8) = *(short8*)o;
}

// ---------------- MFMA GEMM, row-panel, LDS-free, bf16 output --------------
template<int J, int T, int H>
__global__ __launch_bounds__(256)
void gemm_mfma(const ushort* __restrict__ A, const ushort* __restrict__ Bf,
               ushort* __restrict__ Cbf, const float* __restrict__ attS,
               const float* __restrict__ attD, float* __restrict__ as_,
               float* __restrict__ ad_, int M)
{
    constexpr int K = 32 * T;
    constexpr int NN = 16 * J;
    const int l = threadIdx.x & 63;
    const int wid = blockIdx.x * (blockDim.x >> 6) + (threadIdx.x >> 6);
    const int base = wid * 16;
    if (base >= M) return;
    const int lm = l & 15, lg = l >> 4;

    short8 a[T];
    const ushort* ap = A + (size_t)(base + lm) * K + lg * 8;
    #pragma unroll
    for (int t = 0; t < T; ++t) a[t] = *(const short8*)(ap + t * 32);

    f32x4 acc[J];
    #pragma unroll
    for (int j = 0; j < J; ++j) acc[j] = (f32x4){0.f, 0.f, 0.f, 0.f};

    const ushort* bp = Bf + (size_t)l * 8;
    #pragma unroll
    for (int j = 0; j < J; ++j)
        #pragma unroll
        for (int t = 0; t < T; ++t) {
            short8 b = *(const short8*)(bp + (size_t)(j * T + t) * 512);
            acc[j] = __builtin_amdgcn_mfma_f32_16x16x32_bf16(a[t], b, acc[j], 0, 0, 0);
        }

    // epilogue: store bf16 C + fused attention dots (f32 precision)
    float sp[H][4], dp[H][4];
    #pragma unroll
    for (int h = 0; h < H; ++h)
        #pragma unroll
        for (int r = 0; r < 4; ++r) { sp[h][r] = 0.f; dp[h][r] = 0.f; }

    #pragma unroll
    for (int j = 0; j < J; ++j) {
        const int h = j / (J / H);
        const int coff = (j % (J / H)) * 16 + lm;     // col within head
        float ws = attS[h * 64 + coff];
        float wd = attD[h * 64 + coff];
        #pragma unroll
        for (int r = 0; r < 4; ++r) {
            int row = base + lg * 4 + r;
            Cbf[(size_t)row * NN + j * 16 + lm] = f2bf(acc[j][r]);
            sp[h][r] = fmaf(acc[j][r], ws, sp[h][r]);
            dp[h][r] = fmaf(acc[j][r], wd, dp[h][r]);
        }
    }
    #pragma unroll
    for (int h = 0; h < H; ++h)
        #pragma unroll
        for (int r = 0; r < 4; ++r) {
            float s = sp[h][r], d = dp[h][r];
            s += __shfl_xor(s, 1); d += __shfl_xor(d, 1);
            s += __shfl_xor(s, 2); d += __shfl_xor(d, 2);
            s += __shfl_xor(s, 4); d += __shfl_xor(d, 4);
            s += __shfl_xor(s, 8); d += __shfl_xor(d, 8);
            if (lm == 0) {
                int row = base + lg * 4 + r;
                as_[row * H + h] = s;
                ad_[row * H + h] = d;
            }
        }
}

// ---------------- CSR build (real edges only; self-loops implicit) ---------
__global__ __launch_bounds__(256)
void degree_hist(const int* __restrict__ edst, int* __restrict__ deg, int E)
{
    int i = blockIdx.x * blockDim.x + threadIdx.x;
    if (i < E) atomicAdd(&deg[edst[i]], 1);
}

// single-block exclusive scan, 4 elems/thread; also zeroes cursor
__global__ __launch_bounds__(1024)
void scan_rowptr(const int* __restrict__ deg, int* __restrict__ rowptr,
                 int* __restrict__ cursor, int N)
{
    __shared__ int wsums[16];
    __shared__ int s_carry;
    const int tid = threadIdx.x, lane = tid & 63, wid = tid >> 6;
    if (tid == 0) s_carry = 0;
    __syncthreads();
    const int N4 = N >> 2;
    for (int base = 0; base < N4; base += 1024) {
        int i4 = base + tid;
        int4 v = (i4 < N4) ? ((const int4*)deg)[i4] : make_int4(0, 0, 0, 0);
        int tsum = v.x + v.y + v.z + v.w;
        int sc = tsum;
        #pragma unroll
        for (int off = 1; off < 64; off <<= 1) {
            int t = __shfl_up(sc, off);
            if (lane >= off) sc += t;
        }
        if (lane == 63) wsums[wid] = sc;
        __syncthreads();
        if (wid == 0) {
            int wv = (lane < 16) ? wsums[lane] : 0;
            #pragma unroll
            for (int off = 1; off < 16; off <<= 1) {
                int t = __shfl_up(wv, off);
                if (lane >= off) wv += t;
            }
            if (lane < 16) wsums[lane] = wv;
        }
        __syncthreads();
        int wbase = (wid > 0) ? wsums[wid - 1] : 0;
        int excl = s_carry + wbase + sc - tsum;
        if (i4 < N4) {
            int4 o;
            o.x = excl; o.y = excl + v.x; o.z = o.y + v.y; o.w = o.z + v.z;
            ((int4*)rowptr)[i4] = o;
            ((int4*)cursor)[i4] = make_int4(0, 0, 0, 0);
        }
        __syncthreads();
        if (tid == 0) s_carry += wsums[15];
        __syncthreads();
    }
    if (tid == 0) rowptr[N] = s_carry;
}

__global__ __launch_bounds__(256)
void scatter_edges(const int* __restrict__ esrc, const int* __restrict__ edst,
                   const int* __restrict__ rowptr, int* __restrict__ cursor,
                   int* __restrict__ csr_src, int E)
{
    int i = blockIdx.x * blockDim.x + threadIdx.x;
    if (i >= E) return;
    int s = esrc[i], d = edst[i];
    int pos = rowptr[d] + atomicAdd(&cursor[d], 1);
    csr_src[pos] = s;
}

// -------- layer-1 aggregation: wave per dst node; chunked p-dedup ----------
__global__ __launch_bounds__(256)
void aggregate_l1(const int* __restrict__ rowptr, const int* __restrict__ csr_src,
                  const ushort* __restrict__ h1, const float* __restrict__ as_,
                  const float* __restrict__ ad_, const float* __restrict__ bias,
                  ushort* __restrict__ outbf, int N)
{
    int w = (blockIdx.x * blockDim.x + threadIdx.x) >> 6;
    int lane = threadIdx.x & 63;
    if (w >= N) return;
    const int head = lane >> 4;          // 4 heads x 16 lanes
    const int lm = lane & 15;
    const int c0 = lane << 2;            // ushort4 per lane
    const float ad = ad_[w * 4 + head];
    float4 acc;
    float dsum;

    {   // implicit self-loop
        float el = as_[w * 4 + head] + ad;
        el = el > 0.f ? el : LRELU_SLOPE * el;
        float p = __expf(el);
        ushort4 u = *(const ushort4*)(h1 + (size_t)w * 256 + c0);
        acc.x = p * bf2f(u.x); acc.y = p * bf2f(u.y);
        acc.z = p * bf2f(u.z); acc.w = p * bf2f(u.w);
        dsum = p;
    }

    int e = rowptr[w];
    const int e1 = rowptr[w + 1];
    while (e < e1) {
        const int cnt = (e1 - e < 16) ? (e1 - e) : 16;
        // lane (head*16+lm) computes p for (edge lm, head) -- one exp each
        int idx = e + lm; if (idx >= e1) idx = e1 - 1;
        const int s_l = csr_src[idx];
        float el = as_[s_l * 4 + head] + ad;
        el = el > 0.f ? el : LRELU_SLOPE * el;
        const float p_l = __expf(el);
        #pragma unroll
        for (int j = 0; j < 16; ++j) {
            if (j >= cnt) break;                      // wave-uniform
            const float p = __shfl(p_l, j, 16);       // from own head group
            const int sj = __builtin_amdgcn_readlane(s_l, j);   // SGPR
            const ushort4 u = *(const ushort4*)(h1 + (size_t)sj * 256 + c0);
            acc.x = fmaf(p, bf2f(u.x), acc.x);
            acc.y = fmaf(p, bf2f(u.y), acc.y);
            acc.z = fmaf(p, bf2f(u.z), acc.z);
            acc.w = fmaf(p, bf2f(u.w), acc.w);
            dsum += p;
        }
        e += 16;
    }

    const float inv = 1.f / (dsum + 1e-16f);
    const float4 b = *(const float4*)(bias + c0);
    float ox = acc.x * inv + b.x; ox = ox > 0.f ? ox : expm1f(ox);
    float oy = acc.y * inv + b.y; oy = oy > 0.f ? oy : expm1f(oy);
    float oz = acc.z * inv + b.z; oz = oz > 0.f ? oz : expm1f(oz);
    float ow = acc.w * inv + b.w; ow = ow > 0.f ? ow : expm1f(ow);
    ushort4 o;
    o.x = f2bf(ox); o.y = f2bf(oy); o.z = f2bf(oz); o.w = f2bf(ow);
    *(ushort4*)(outbf + (size_t)w * 256 + c0) = o;
}

// -------- layer-2 aggregation + scoring head; chunked p-dedup --------------
__global__ __launch_bounds__(256)
void aggregate_l2(const int* __restrict__ rowptr, const int* __restrict__ csr_src,
                  const ushort* __restrict__ h2, const float* __restrict__ as_,
                  const float* __restrict__ ad_, const float* __restrict__ b2,
                  const float* __restrict__ Wsv, const float* __restrict__ bs,
                  float* __restrict__ hout, float* __restrict__ scores, int N)
{
    int w = (blockIdx.x * blockDim.x + threadIdx.x) >> 6;
    int lane = threadIdx.x & 63;
    if (w >= N) return;
    const int lm = lane & 15;
    const float ad = ad_[w];
    float acc, dsum;
    {   // implicit self-loop
        float el = as_[w] + ad;
        el = el > 0.f ? el : LRELU_SLOPE * el;
        float p = __expf(el);
        acc = p * bf2f(h2[(size_t)w * 64 + lane]);
        dsum = p;
    }
    int e = rowptr[w];
    const int e1 = rowptr[w + 1];
    while (e < e1) {
        const int cnt = (e1 - e < 16) ? (e1 - e) : 16;
        int idx = e + lm; if (idx >= e1) idx = e1 - 1;
        const int s_l = csr_src[idx];
        float el = as_[s_l] + ad;
        el = el > 0.f ? el : LRELU_SLOPE * el;
        const float p_l = __expf(el);
        #pragma unroll
        for (int j = 0; j < 16; ++j) {
            if (j >= cnt) break;                      // wave-uniform
            const float p = readlane_f(p_l, j);       // SGPR (uniform)
            const int sj = __builtin_amdgcn_readlane(s_l, j);
            acc = fmaf(p, bf2f(h2[(size_t)sj * 64 + lane]), acc);
            dsum += p;
        }
        e += 16;
    }
    float v = acc / (dsum + 1e-16f) + b2[lane];
    v = v > 0.f ? v : expm1f(v);
    hout[(size_t)w * 64 + lane] = v;
    float sc = v * Wsv[lane];
    #pragma unroll
    for (int off = 32; off; off >>= 1) sc += __shfl_down(sc, off);
    if (lane == 0) scores[w] = sc + bs[0];
}

// ---------------------------------------------------------------------------
extern "C" void kernel_launch(void* const* d_in, const int* in_sizes, int n_in,
                              void* d_out, int out_size, void* d_ws, size_t ws_size,
                              hipStream_t stream)
{
    const float* x    = (const float*)d_in[0];
    const int*   ei   = (const int*)d_in[1];
    const float* W1   = (const float*)d_in[2];
    const float* as1w = (const float*)d_in[3];
    const float* ad1w = (const float*)d_in[4];
    const float* b1   = (const float*)d_in[5];
    const float* W2   = (const float*)d_in[6];
    const float* as2w = (const float*)d_in[7];
    const float* ad2w = (const float*)d_in[8];
    const float* b2   = (const float*)d_in[9];
    const float* Ws   = (const float*)d_in[10];
    const float* bs   = (const float*)d_in[11];

    const int N  = in_sizes[0] / 128;   // 50000
    const int E  = in_sizes[1] / 2;     // 800000
    const int* esrc = ei;
    const int* edst = ei + E;

    // ---- workspace layout (16B-aligned chunks) ----
    ushort* h1bf  = (ushort*)d_ws;                       // N*256 bf16
    ushort* hl1bf = h1bf + (size_t)N * 256;              // N*256 bf16
    ushort* xbf   = hl1bf + (size_t)N * 256;             // N*128 bf16
    ushort* h2bf  = xbf + (size_t)N * 128;               // N*64 bf16
    ushort* bfr1  = h2bf + (size_t)N * 64;               // 32768
    ushort* bfr2  = bfr1 + 32768;                        // 16384
    float*  as1   = (float*)(bfr2 + 16384);              // N*4
    float*  ad1   = as1 + (size_t)N * 4;                 // N*4
    float*  as2   = ad1 + (size_t)N * 4;                 // N
    float*  ad2   = as2 + N;                             // N
    int*    deg    = (int*)(ad2 + N);                    // N
    int*    cursor = deg + N;                            // N
    int*    rowptr = cursor + N;                         // N+1 (+pad)
    int*    csr_src= rowptr + N + 4;                     // E

    float* hout   = (float*)d_out;                       // N*64
    float* scores = hout + (size_t)N * 64;               // N

    // ---------------- CSR build (shared by both layers) ----------------
    hipMemsetAsync(deg, 0, (size_t)N * sizeof(int), stream);
    degree_hist<<<(E + 255) / 256, 256, 0, stream>>>(edst, deg, E);
    scan_rowptr<<<1, 1024, 0, stream>>>(deg, rowptr, cursor, N);
    scatter_edges<<<(E + 255) / 256, 256, 0, stream>>>(
        esrc, edst, rowptr, cursor, csr_src, E);

    // ---------------- input conversion / weight pre-fragmentation -------
    conv_bf16<<<((size_t)N * 128 / 4 + 255) / 256, 256, 0, stream>>>(
        x, xbf, N * 128);
    prefrag<<<(16 * 4 * 64 + 255) / 256, 256, 0, stream>>>(W1, bfr1, 16, 4, 256);
    prefrag<<<(4 * 8 * 64 + 255) / 256, 256, 0, stream>>>(W2, bfr2, 4, 8, 64);

    // ---------------- layer 1 ----------------
    gemm_mfma<16, 4, 4><<<(N / 16 + 3) / 4, 256, 0, stream>>>(
        xbf, bfr1, h1bf, as1w, ad1w, as1, ad1, N);
    aggregate_l1<<<((size_t)N * 64 + 255) / 256, 256, 0, stream>>>(
        rowptr, csr_src, h1bf, as1, ad1, b1, hl1bf, N);

    // ---------------- layer 2 ----------------
    gemm_mfma<4, 8, 1><<<(N / 16 + 3) / 4, 256, 0, stream>>>(
        hl1bf, bfr2, h2bf, as2w, ad2w, as2, ad2, N);
    aggregate_l2<<<((size_t)N * 64 + 255) / 256, 256, 0, stream>>>(
        rowptr, csr_src, h2bf, as2, ad2, b2, Ws, bs, hout, scores, N);
}

// Round 6
// 266.215 us; speedup vs baseline: 1.0955x; 1.0955x over previous
//
#include <hip/hip_runtime.h>
#include <hip/hip_bf16.h>
#include <math.h>

// ---------------------------------------------------------------------------
// DualHeadGAT R6: R4 gather structure (4x unrolled, max MLP) + per-edge
// softmax coefficients precomputed in a separate streaming pass (edge_coef),
// conv_bf16 fused into gemm1 (f32 A loaded+converted in-register).
// bf16 feature gathers, MFMA GEMMs with fused att dots, CSR aggregation,
// implicit self-loops, deferred softmax normalization (exact).
// N=50000, IN=128, E=800000. f32 in/out, int32 edges.
// ---------------------------------------------------------------------------

#define LRELU_SLOPE 0.2f

typedef __attribute__((ext_vector_type(8))) short short8;   // 8 bf16 = 4 VGPR
typedef __attribute__((ext_vector_type(4))) float f32x4;

__device__ inline ushort f2bf(float f) {            // RNE f32 -> bf16
    uint u = __float_as_uint(f);
    return (ushort)((u + 0x7FFFu + ((u >> 16) & 1u)) >> 16);
}
__device__ inline float bf2f(ushort u) {
    return __uint_as_float(((uint)u) << 16);
}

// ------- pre-fragment W[K][16J] (f32, row-major) into MFMA B-frag order ----
__global__ __launch_bounds__(256)
void prefrag(const float* __restrict__ W, ushort* __restrict__ out,
             int J, int T, int ldn)
{
    int tid = blockIdx.x * blockDim.x + threadIdx.x;
    if (tid >= J * T * 64) return;
    int l = tid & 63, jt = tid >> 6;
    int t = jt % T, j = jt / T;
    int n = j * 16 + (l & 15);
    int k0 = t * 32 + (l >> 4) * 8;
    ushort o[8];
    #pragma unroll
    for (int b = 0; b < 8; ++b) o[b] = f2bf(W[(size_t)(k0 + b) * ldn + n]);
    *(short8*)(out + (size_t)tid * 8) = *(short8*)o;
}

// ---------------- MFMA GEMM, row-panel, LDS-free, bf16 output --------------
// AF32: A is f32 (converted to bf16 in-register; rows are single-use).
template<int J, int T, int H, bool AF32>
__global__ __launch_bounds__(256)
void gemm_mfma(const void* __restrict__ Araw, const ushort* __restrict__ Bf,
               ushort* __restrict__ Cbf, const float* __restrict__ attS,
               const float* __restrict__ attD, float* __restrict__ as_,
               float* __restrict__ ad_, int M)
{
    constexpr int K = 32 * T;
    constexpr int NN = 16 * J;
    const int l = threadIdx.x & 63;
    const int wid = blockIdx.x * (blockDim.x >> 6) + (threadIdx.x >> 6);
    const int base = wid * 16;
    if (base >= M) return;
    const int lm = l & 15, lg = l >> 4;

    short8 a[T];
    if constexpr (AF32) {
        const float* ap = (const float*)Araw + (size_t)(base + lm) * K + lg * 8;
        #pragma unroll
        for (int t = 0; t < T; ++t) {
            float4 v0 = *(const float4*)(ap + t * 32);
            float4 v1 = *(const float4*)(ap + t * 32 + 4);
            ushort o[8];
            o[0] = f2bf(v0.x); o[1] = f2bf(v0.y); o[2] = f2bf(v0.z); o[3] = f2bf(v0.w);
            o[4] = f2bf(v1.x); o[5] = f2bf(v1.y); o[6] = f2bf(v1.z); o[7] = f2bf(v1.w);
            a[t] = *(short8*)o;
        }
    } else {
        const ushort* ap = (const ushort*)Araw + (size_t)(base + lm) * K + lg * 8;
        #pragma unroll
        for (int t = 0; t < T; ++t) a[t] = *(const short8*)(ap + t * 32);
    }

    f32x4 acc[J];
    #pragma unroll
    for (int j = 0; j < J; ++j) acc[j] = (f32x4){0.f, 0.f, 0.f, 0.f};

    const ushort* bp = Bf + (size_t)l * 8;
    #pragma unroll
    for (int j = 0; j < J; ++j)
        #pragma unroll
        for (int t = 0; t < T; ++t) {
            short8 b = *(const short8*)(bp + (size_t)(j * T + t) * 512);
            acc[j] = __builtin_amdgcn_mfma_f32_16x16x32_bf16(a[t], b, acc[j], 0, 0, 0);
        }

    // epilogue: store bf16 C + fused attention dots (f32 precision)
    float sp[H][4], dp[H][4];
    #pragma unroll
    for (int h = 0; h < H; ++h)
        #pragma unroll
        for (int r = 0; r < 4; ++r) { sp[h][r] = 0.f; dp[h][r] = 0.f; }

    #pragma unroll
    for (int j = 0; j < J; ++j) {
        const int h = j / (J / H);
        const int coff = (j % (J / H)) * 16 + lm;     // col within head
        float ws = attS[h * 64 + coff];
        float wd = attD[h * 64 + coff];
        #pragma unroll
        for (int r = 0; r < 4; ++r) {
            int row = base + lg * 4 + r;
            Cbf[(size_t)row * NN + j * 16 + lm] = f2bf(acc[j][r]);
            sp[h][r] = fmaf(acc[j][r], ws, sp[h][r]);
            dp[h][r] = fmaf(acc[j][r], wd, dp[h][r]);
        }
    }
    #pragma unroll
    for (int h = 0; h < H; ++h)
        #pragma unroll
        for (int r = 0; r < 4; ++r) {
            float s = sp[h][r], d = dp[h][r];
            s += __shfl_xor(s, 1); d += __shfl_xor(d, 1);
            s += __shfl_xor(s, 2); d += __shfl_xor(d, 2);
            s += __shfl_xor(s, 4); d += __shfl_xor(d, 4);
            s += __shfl_xor(s, 8); d += __shfl_xor(d, 8);
            if (lm == 0) {
                int row = base + lg * 4 + r;
                as_[row * H + h] = s;
                ad_[row * H + h] = d;
            }
        }
}

// ---------------- CSR build (real edges only; self-loops implicit) ---------
__global__ __launch_bounds__(256)
void degree_hist(const int* __restrict__ edst, int* __restrict__ deg, int E)
{
    int i = blockIdx.x * blockDim.x + threadIdx.x;
    if (i < E) atomicAdd(&deg[edst[i]], 1);
}

// single-block exclusive scan, 4 elems/thread; also zeroes cursor
__global__ __launch_bounds__(1024)
void scan_rowptr(const int* __restrict__ deg, int* __restrict__ rowptr,
                 int* __restrict__ cursor, int N)
{
    __shared__ int wsums[16];
    __shared__ int s_carry;
    const int tid = threadIdx.x, lane = tid & 63, wid = tid >> 6;
    if (tid == 0) s_carry = 0;
    __syncthreads();
    const int N4 = N >> 2;
    for (int base = 0; base < N4; base += 1024) {
        int i4 = base + tid;
        int4 v = (i4 < N4) ? ((const int4*)deg)[i4] : make_int4(0, 0, 0, 0);
        int tsum = v.x + v.y + v.z + v.w;
        int sc = tsum;
        #pragma unroll
        for (int off = 1; off < 64; off <<= 1) {
            int t = __shfl_up(sc, off);
            if (lane >= off) sc += t;
        }
        if (lane == 63) wsums[wid] = sc;
        __syncthreads();
        if (wid == 0) {
            int wv = (lane < 16) ? wsums[lane] : 0;
            #pragma unroll
            for (int off = 1; off < 16; off <<= 1) {
                int t = __shfl_up(wv, off);
                if (lane >= off) wv += t;
            }
            if (lane < 16) wsums[lane] = wv;
        }
        __syncthreads();
        int wbase = (wid > 0) ? wsums[wid - 1] : 0;
        int excl = s_carry + wbase + sc - tsum;
        if (i4 < N4) {
            int4 o;
            o.x = excl; o.y = excl + v.x; o.z = o.y + v.y; o.w = o.z + v.z;
            ((int4*)rowptr)[i4] = o;
            ((int4*)cursor)[i4] = make_int4(0, 0, 0, 0);
        }
        __syncthreads();
        if (tid == 0) s_carry += wsums[15];
        __syncthreads();
    }
    if (tid == 0) rowptr[N] = s_carry;
}

__global__ __launch_bounds__(256)
void scatter_edges(const int* __restrict__ esrc, const int* __restrict__ edst,
                   const int* __restrict__ rowptr, int* __restrict__ cursor,
                   int* __restrict__ csr_src, int* __restrict__ csr_dst, int E)
{
    int i = blockIdx.x * blockDim.x + threadIdx.x;
    if (i >= E) return;
    int s = esrc[i], d = edst[i];
    int pos = rowptr[d] + atomicAdd(&cursor[d], 1);
    csr_src[pos] = s;
    csr_dst[pos] = d;
}

// ---- per-edge softmax coefficients, layer 1 (4 heads), streaming ----------
__global__ __launch_bounds__(256)
void edge_coef_l1(const int* __restrict__ csr_src, const int* __restrict__ csr_dst,
                  const float* __restrict__ as_, const float* __restrict__ ad_,
                  float* __restrict__ p1, int E)
{
    int i = blockIdx.x * blockDim.x + threadIdx.x;
    if (i >= E) return;
    int s = csr_src[i], d = csr_dst[i];
    float4 a = *(const float4*)(as_ + (size_t)s * 4);
    float4 b = *(const float4*)(ad_ + (size_t)d * 4);
    float4 o;
    float e0 = a.x + b.x; e0 = e0 > 0.f ? e0 : LRELU_SLOPE * e0; o.x = __expf(e0);
    float e1 = a.y + b.y; e1 = e1 > 0.f ? e1 : LRELU_SLOPE * e1; o.y = __expf(e1);
    float e2 = a.z + b.z; e2 = e2 > 0.f ? e2 : LRELU_SLOPE * e2; o.z = __expf(e2);
    float e3 = a.w + b.w; e3 = e3 > 0.f ? e3 : LRELU_SLOPE * e3; o.w = __expf(e3);
    *(float4*)(p1 + (size_t)i * 4) = o;
}

// ---- per-edge softmax coefficients, layer 2 (1 head), streaming -----------
__global__ __launch_bounds__(256)
void edge_coef_l2(const int* __restrict__ csr_src, const int* __restrict__ csr_dst,
                  const float* __restrict__ as_, const float* __restrict__ ad_,
                  float* __restrict__ p2, int E)
{
    int i = blockIdx.x * blockDim.x + threadIdx.x;
    if (i >= E) return;
    float e0 = as_[csr_src[i]] + ad_[csr_dst[i]];
    e0 = e0 > 0.f ? e0 : LRELU_SLOPE * e0;
    p2[i] = __expf(e0);
}

// -------- layer-1 aggregation: wave per dst node; precomputed p ------------
__global__ __launch_bounds__(256)
void aggregate_l1(const int* __restrict__ rowptr, const int* __restrict__ csr_src,
                  const float* __restrict__ p1, const ushort* __restrict__ h1,
                  const float* __restrict__ as_, const float* __restrict__ ad_,
                  const float* __restrict__ bias, ushort* __restrict__ outbf, int N)
{
    int w = (blockIdx.x * blockDim.x + threadIdx.x) >> 6;
    int lane = threadIdx.x & 63;
    if (w >= N) return;
    const int head = lane >> 4;          // 4 heads x 16 lanes
    const int c0 = lane << 2;            // ushort4 per lane
    float4 acc;
    float dsum;

    {   // implicit self-loop
        float el = as_[w * 4 + head] + ad_[w * 4 + head];
        el = el > 0.f ? el : LRELU_SLOPE * el;
        float p = __expf(el);
        ushort4 u = *(const ushort4*)(h1 + (size_t)w * 256 + c0);
        acc.x = p * bf2f(u.x); acc.y = p * bf2f(u.y);
        acc.z = p * bf2f(u.z); acc.w = p * bf2f(u.w);
        dsum = p;
    }

    int e = rowptr[w];
    const int e1 = rowptr[w + 1];
    for (; e + 3 < e1; e += 4) {         // 4x unroll for MLP
        int s0 = csr_src[e],     s1 = csr_src[e + 1];
        int s2 = csr_src[e + 2], s3 = csr_src[e + 3];
        float p0 = p1[(size_t)(e + 0) * 4 + head];
        float p1v = p1[(size_t)(e + 1) * 4 + head];
        float p2 = p1[(size_t)(e + 2) * 4 + head];
        float p3 = p1[(size_t)(e + 3) * 4 + head];
        ushort4 u0 = *(const ushort4*)(h1 + (size_t)s0 * 256 + c0);
        ushort4 u1 = *(const ushort4*)(h1 + (size_t)s1 * 256 + c0);
        ushort4 u2 = *(const ushort4*)(h1 + (size_t)s2 * 256 + c0);
        ushort4 u3 = *(const ushort4*)(h1 + (size_t)s3 * 256 + c0);
        acc.x = fmaf(p0, bf2f(u0.x), acc.x); acc.y = fmaf(p0, bf2f(u0.y), acc.y);
        acc.z = fmaf(p0, bf2f(u0.z), acc.z); acc.w = fmaf(p0, bf2f(u0.w), acc.w);
        acc.x = fmaf(p1v, bf2f(u1.x), acc.x); acc.y = fmaf(p1v, bf2f(u1.y), acc.y);
        acc.z = fmaf(p1v, bf2f(u1.z), acc.z); acc.w = fmaf(p1v, bf2f(u1.w), acc.w);
        acc.x = fmaf(p2, bf2f(u2.x), acc.x); acc.y = fmaf(p2, bf2f(u2.y), acc.y);
        acc.z = fmaf(p2, bf2f(u2.z), acc.z); acc.w = fmaf(p2, bf2f(u2.w), acc.w);
        acc.x = fmaf(p3, bf2f(u3.x), acc.x); acc.y = fmaf(p3, bf2f(u3.y), acc.y);
        acc.z = fmaf(p3, bf2f(u3.z), acc.z); acc.w = fmaf(p3, bf2f(u3.w), acc.w);
        dsum += (p0 + p1v) + (p2 + p3);
    }
    for (; e < e1; ++e) {
        int s0 = csr_src[e];
        float p0 = p1[(size_t)e * 4 + head];
        ushort4 u0 = *(const ushort4*)(h1 + (size_t)s0 * 256 + c0);
        acc.x = fmaf(p0, bf2f(u0.x), acc.x); acc.y = fmaf(p0, bf2f(u0.y), acc.y);
        acc.z = fmaf(p0, bf2f(u0.z), acc.z); acc.w = fmaf(p0, bf2f(u0.w), acc.w);
        dsum += p0;
    }
    const float inv = 1.f / (dsum + 1e-16f);
    const float4 b = *(const float4*)(bias + c0);
    float ox = acc.x * inv + b.x; ox = ox > 0.f ? ox : expm1f(ox);
    float oy = acc.y * inv + b.y; oy = oy > 0.f ? oy : expm1f(oy);
    float oz = acc.z * inv + b.z; oz = oz > 0.f ? oz : expm1f(oz);
    float ow = acc.w * inv + b.w; ow = ow > 0.f ? ow : expm1f(ow);
    ushort4 o;
    o.x = f2bf(ox); o.y = f2bf(oy); o.z = f2bf(oz); o.w = f2bf(ow);
    *(ushort4*)(outbf + (size_t)w * 256 + c0) = o;
}

// -------- layer-2 aggregation + scoring head; precomputed p ----------------
__global__ __launch_bounds__(256)
void aggregate_l2(const int* __restrict__ rowptr, const int* __restrict__ csr_src,
                  const float* __restrict__ p2, const ushort* __restrict__ h2,
                  const float* __restrict__ as_, const float* __restrict__ ad_,
                  const float* __restrict__ b2, const float* __restrict__ Wsv,
                  const float* __restrict__ bs, float* __restrict__ hout,
                  float* __restrict__ scores, int N)
{
    int w = (blockIdx.x * blockDim.x + threadIdx.x) >> 6;
    int lane = threadIdx.x & 63;
    if (w >= N) return;
    float acc, dsum;
    {   // implicit self-loop
        float el = as_[w] + ad_[w];
        el = el > 0.f ? el : LRELU_SLOPE * el;
        float p = __expf(el);
        acc = p * bf2f(h2[(size_t)w * 64 + lane]);
        dsum = p;
    }
    int e = rowptr[w];
    const int e1 = rowptr[w + 1];
    for (; e + 3 < e1; e += 4) {
        int s0 = csr_src[e],     s1 = csr_src[e + 1];
        int s2 = csr_src[e + 2], s3 = csr_src[e + 3];
        float p0 = p2[e], p1 = p2[e + 1], p2v = p2[e + 2], p3 = p2[e + 3];
        acc = fmaf(p0, bf2f(h2[(size_t)s0 * 64 + lane]), acc);
        acc = fmaf(p1, bf2f(h2[(size_t)s1 * 64 + lane]), acc);
        acc = fmaf(p2v, bf2f(h2[(size_t)s2 * 64 + lane]), acc);
        acc = fmaf(p3, bf2f(h2[(size_t)s3 * 64 + lane]), acc);
        dsum += (p0 + p1) + (p2v + p3);
    }
    for (; e < e1; ++e) {
        int s0 = csr_src[e];
        float p0 = p2[e];
        acc = fmaf(p0, bf2f(h2[(size_t)s0 * 64 + lane]), acc);
        dsum += p0;
    }
    float v = acc / (dsum + 1e-16f) + b2[lane];
    v = v > 0.f ? v : expm1f(v);
    hout[(size_t)w * 64 + lane] = v;
    float sc = v * Wsv[lane];
    #pragma unroll
    for (int off = 32; off; off >>= 1) sc += __shfl_down(sc, off);
    if (lane == 0) scores[w] = sc + bs[0];
}

// ---------------------------------------------------------------------------
extern "C" void kernel_launch(void* const* d_in, const int* in_sizes, int n_in,
                              void* d_out, int out_size, void* d_ws, size_t ws_size,
                              hipStream_t stream)
{
    const float* x    = (const float*)d_in[0];
    const int*   ei   = (const int*)d_in[1];
    const float* W1   = (const float*)d_in[2];
    const float* as1w = (const float*)d_in[3];
    const float* ad1w = (const float*)d_in[4];
    const float* b1   = (const float*)d_in[5];
    const float* W2   = (const float*)d_in[6];
    const float* as2w = (const float*)d_in[7];
    const float* ad2w = (const float*)d_in[8];
    const float* b2   = (const float*)d_in[9];
    const float* Ws   = (const float*)d_in[10];
    const float* bs   = (const float*)d_in[11];

    const int N  = in_sizes[0] / 128;   // 50000
    const int E  = in_sizes[1] / 2;     // 800000
    const int* esrc = ei;
    const int* edst = ei + E;

    // ---- workspace layout (16B-aligned chunks) ----
    ushort* h1bf  = (ushort*)d_ws;                       // N*256 bf16
    ushort* hl1bf = h1bf + (size_t)N * 256;              // N*256 bf16
    ushort* h2bf  = hl1bf + (size_t)N * 256;             // N*64 bf16
    ushort* bfr1  = h2bf + (size_t)N * 64;               // 32768
    ushort* bfr2  = bfr1 + 32768;                        // 16384
    float*  as1   = (float*)(bfr2 + 16384);              // N*4
    float*  ad1   = as1 + (size_t)N * 4;                 // N*4
    float*  as2   = ad1 + (size_t)N * 4;                 // N
    float*  ad2   = as2 + N;                             // N
    float*  p1    = ad2 + N;                             // E*4
    float*  p2    = p1 + (size_t)E * 4;                  // E
    int*    deg    = (int*)(p2 + E);                     // N
    int*    cursor = deg + N;                            // N
    int*    rowptr = cursor + N;                         // N+1 (+pad)
    int*    csr_src= rowptr + N + 4;                     // E
    int*    csr_dst= csr_src + E;                        // E

    float* hout   = (float*)d_out;                       // N*64
    float* scores = hout + (size_t)N * 64;               // N

    // ---------------- CSR build (shared by both layers) ----------------
    hipMemsetAsync(deg, 0, (size_t)N * sizeof(int), stream);
    degree_hist<<<(E + 255) / 256, 256, 0, stream>>>(edst, deg, E);
    scan_rowptr<<<1, 1024, 0, stream>>>(deg, rowptr, cursor, N);
    scatter_edges<<<(E + 255) / 256, 256, 0, stream>>>(
        esrc, edst, rowptr, cursor, csr_src, csr_dst, E);

    // ---------------- weight pre-fragmentation -------
    prefrag<<<(16 * 4 * 64 + 255) / 256, 256, 0, stream>>>(W1, bfr1, 16, 4, 256);
    prefrag<<<(4 * 8 * 64 + 255) / 256, 256, 0, stream>>>(W2, bfr2, 4, 8, 64);

    // ---------------- layer 1 ----------------
    gemm_mfma<16, 4, 4, true><<<(N / 16 + 3) / 4, 256, 0, stream>>>(
        x, bfr1, h1bf, as1w, ad1w, as1, ad1, N);
    edge_coef_l1<<<(E + 255) / 256, 256, 0, stream>>>(
        csr_src, csr_dst, as1, ad1, p1, E);
    aggregate_l1<<<((size_t)N * 64 + 255) / 256, 256, 0, stream>>>(
        rowptr, csr_src, p1, h1bf, as1, ad1, b1, hl1bf, N);

    // ---------------- layer 2 ----------------
    gemm_mfma<4, 8, 1, false><<<(N / 16 + 3) / 4, 256, 0, stream>>>(
        hl1bf, bfr2, h2bf, as2w, ad2w, as2, ad2, N);
    edge_coef_l2<<<(E + 255) / 256, 256, 0, stream>>>(
        csr_src, csr_dst, as2, ad2, p2, E);
    aggregate_l2<<<((size_t)N * 64 + 255) / 256, 256, 0, stream>>>(
        rowptr, csr_src, p2, h2bf, as2, ad2, b2, Ws, bs, hout, scores, N);
}